// Round 15
// baseline (184.676 us; speedup 1.0000x reference)
//
#include <hip/hip_runtime.h>

#define NN 100000
#define NE 1600000
#define D  128
#define CAP 32
#define OVF_CAP 65536
#define NXCD 8
#define NPX  (NN / NXCD)        // 12500 nodes per XCD slice
#define RBLK 256                // route blocks
#define EPB  (NE / RBLK)        // 6250 edges per route block
#define LCAP 1024               // per (block,slice) fifo capacity (mean 781, +8.7 sigma)

// ---- W3 (route+fill) workspace layout, ~47.8 MB ----
#define W3_XH    0u             // NN*D bf16 = 25,600,000
#define W3_SLOTS 25600000u      // NN*CAP u32 = 12,800,000
#define W3_CUR   38400000u      // NN u32 (+pad; memset 400,128 covers OVFN)
#define W3_OVFN  38800000u
#define W3_OVF   38800128u      // OVF_CAP*8
#define W3_BH    39324416u      // 32,768
#define W3_FCNT  39357184u      // RBLK*8 u32 = 8,192
#define W3_FIFO  39365376u      // RBLK*8*LCAP*4 = 8,388,608
#define W3_NEED  47753984u

// ---- W2 (r14-proven) workspace layout, ~39.4 MB ----
#define W2_XH    0u
#define W2_SLOTS 25600000u
#define W2_CUR   38400000u
#define W2_OVFN  38800000u
#define W2_OVF   38800128u
#define W2_BH    39324416u
#define W2_NEED  39357184u

#define SP_SCAT  2048
#define SP_CASTX 6250
#define SP_GRID  (SP_SCAT + SP_CASTX + 8)

typedef __attribute__((ext_vector_type(8))) short bf16x8;
typedef __attribute__((ext_vector_type(4))) float f32x4;

__device__ __forceinline__ unsigned short f2bf(float f) {   // RNE f32 -> bf16
    union { float f; unsigned u; } v; v.f = f;
    unsigned r = v.u + 0x7fffu + ((v.u >> 16) & 1u);
    return (unsigned short)(r >> 16);
}
__device__ __forceinline__ float bfbits(unsigned hi) {
    union { unsigned u; float f; } v; v.u = hi; return v.f;
}

__device__ __forceinline__ void cast_x_body(const float* x, unsigned* xh4, int i) {
    const float4 v0 = *((const float4*)x + i * 2);
    const float4 v1 = *((const float4*)x + i * 2 + 1);
    uint4 o;
    o.x = f2bf(v0.x) | ((unsigned)f2bf(v0.y) << 16);
    o.y = f2bf(v0.z) | ((unsigned)f2bf(v0.w) << 16);
    o.z = f2bf(v1.x) | ((unsigned)f2bf(v1.y) << 16);
    o.w = f2bf(v1.z) | ((unsigned)f2bf(v1.w) << 16);
    *((uint4*)xh4 + i) = o;
}
__device__ __forceinline__ void cast_w_body(const float* W, unsigned short* Bh, int idx) {
    const int j = idx >> 4, kc = idx & 15;
    const float4 w0 = *(const float4*)(W + (size_t)j * D + kc * 8);
    const float4 w1 = *(const float4*)(W + (size_t)j * D + kc * 8 + 4);
    unsigned short* o = Bh + ((size_t)(kc * 128 + j)) * 8;
    o[0] = f2bf(w0.x); o[1] = f2bf(w0.y); o[2] = f2bf(w0.z); o[3] = f2bf(w0.w);
    o[4] = f2bf(w1.x); o[5] = f2bf(w1.y); o[6] = f2bf(w1.z); o[7] = f2bf(w1.w);
}

// =============== W3 K1: route edges into per-(block,slice) FIFOs + casts ===============
__global__ __launch_bounds__(256) void k_route_prep(const float* __restrict__ x,
                                                    const float* __restrict__ W,
                                                    const int* __restrict__ ei,
                                                    unsigned* __restrict__ cur,
                                                    unsigned* __restrict__ slots,
                                                    unsigned* __restrict__ ovfn,
                                                    unsigned* __restrict__ ovf,
                                                    unsigned* __restrict__ fcnt,
                                                    unsigned* __restrict__ fifo,
                                                    unsigned* __restrict__ xh4,
                                                    unsigned short* __restrict__ Bh) {
    __shared__ unsigned lbuf[8][LCAP];
    __shared__ unsigned lcnt[8];
    const int bid = blockIdx.x, t = threadIdx.x;
    if (bid < RBLK) {
        if (t < 8) lcnt[t] = 0;
        __syncthreads();
        const int base = bid * EPB;
        for (int i = t; i < EPB; i += 256) {
            const int e = base + i;
            const unsigned d   = (unsigned)ei[NE + e];
            const unsigned src = (unsigned)ei[e];
            const unsigned s   = d / NPX;
            const unsigned entry = ((d - s * NPX) << 17) | src;
            const unsigned pos = atomicAdd(&lcnt[s], 1u);
            if (pos < LCAP) lbuf[s][pos] = entry;
            else {                         // ~never: direct global scatter fallback
                const unsigned p = atomicAdd(&cur[d], 1u);
                if (p < CAP) slots[(size_t)d * CAP + p] = src;
                else {
                    const unsigned o = atomicAdd(ovfn, 1u);
                    if (o < OVF_CAP) { ovf[2 * o] = d; ovf[2 * o + 1] = src; }
                }
            }
        }
        __syncthreads();
        #pragma unroll
        for (int s = 0; s < 8; ++s) {      // coalesced streaming flush
            const unsigned cnt = min(lcnt[s], (unsigned)LCAP);
            unsigned* dst = fifo + ((size_t)bid * 8 + s) * LCAP;
            for (unsigned i = t; i < cnt; i += 256) dst[i] = lbuf[s][i];
        }
        if (t < 8) fcnt[bid * 8 + t] = min(lcnt[t], (unsigned)LCAP);
    } else if (bid < RBLK + SP_CASTX) {
        cast_x_body(x, xh4, (bid - RBLK) * 256 + t);
    } else {
        const int idx = (bid - RBLK - SP_CASTX) * 256 + t;
        if (idx < 128 * 16) cast_w_body(W, Bh, idx);
    }
}

// =============== W3 K2: slot fill (XCD-local, low-pollution reads) ===============
__global__ __launch_bounds__(256) void k_slot_fill(const unsigned* __restrict__ fcnt,
                                                   const unsigned* __restrict__ fifo,
                                                   unsigned* __restrict__ cur,
                                                   unsigned* __restrict__ slots,
                                                   unsigned* __restrict__ ovfn,
                                                   unsigned* __restrict__ ovf) {
    const int s = blockIdx.x & 7;          // slice == XCD (round-robin heuristic)
    const int r = blockIdx.x >> 3;         // source route block
    const unsigned cnt = fcnt[r * 8 + s];
    const unsigned* src = fifo + ((size_t)r * 8 + s) * LCAP;
    for (unsigned i = threadIdx.x; i < cnt; i += 256) {
        const unsigned entry = src[i];
        const unsigned d  = (unsigned)s * NPX + (entry >> 17);
        const unsigned sv = entry & 0x1FFFFu;
        const unsigned p = atomicAdd(&cur[d], 1u);
        if (p < CAP) slots[(size_t)d * CAP + p] = sv;
        else {
            const unsigned o = atomicAdd(ovfn, 1u);
            if (o < OVF_CAP) { ovf[2 * o] = d; ovf[2 * o + 1] = sv; }
        }
    }
}

// =============== W2 K1 (r14-proven fallback): fused slot scatter + casts ===============
__global__ __launch_bounds__(256) void k_scatter_prep(const float* __restrict__ x,
                                                      const float* __restrict__ W,
                                                      const int* __restrict__ ei,
                                                      unsigned* __restrict__ cur,
                                                      unsigned* __restrict__ slots,
                                                      unsigned* __restrict__ ovfn,
                                                      unsigned* __restrict__ ovf,
                                                      unsigned* __restrict__ xh4,
                                                      unsigned short* __restrict__ Bh) {
    const int bid = blockIdx.x, t = threadIdx.x;
    if (bid < SP_SCAT) {
        const unsigned lo = (bid & 7) * NPX;
        const int nth = (SP_SCAT >> 3) * 256;
        const int tid = (bid >> 3) * 256 + t;

        auto put = [&](unsigned d, unsigned s) {
            if (d - lo < NPX) {
                const unsigned p = atomicAdd(&cur[d], 1u);
                if (p < CAP) slots[(size_t)d * CAP + p] = s;
                else {
                    const unsigned o = atomicAdd(ovfn, 1u);
                    if (o < OVF_CAP) { ovf[2 * o] = d; ovf[2 * o + 1] = s; }
                }
            }
        };

        int e = tid;
        for (; e + 3 * nth < NE; e += 4 * nth) {
            const unsigned d0 = (unsigned)ei[NE + e];
            const unsigned d1 = (unsigned)ei[NE + e + nth];
            const unsigned d2 = (unsigned)ei[NE + e + 2 * nth];
            const unsigned d3 = (unsigned)ei[NE + e + 3 * nth];
            const unsigned s0 = (unsigned)ei[e];
            const unsigned s1 = (unsigned)ei[e + nth];
            const unsigned s2 = (unsigned)ei[e + 2 * nth];
            const unsigned s3 = (unsigned)ei[e + 3 * nth];
            put(d0, s0); put(d1, s1); put(d2, s2); put(d3, s3);
        }
        for (; e < NE; e += nth) put((unsigned)ei[NE + e], (unsigned)ei[e]);
    } else if (bid < SP_SCAT + SP_CASTX) {
        cast_x_body(x, xh4, (bid - SP_SCAT) * 256 + t);
    } else {
        const int idx = (bid - SP_SCAT - SP_CASTX) * 256 + t;
        if (idx < 128 * 16) cast_w_body(W, Bh, idx);
    }
}

// =============== aggregate: 2 nodes/wave, quarter-wave uint4 (r14-proven) ===============
#define ADD8A(v, A) { A[0] += bfbits((v).x << 16); A[1] += bfbits((v).x & 0xffff0000u); \
                      A[2] += bfbits((v).y << 16); A[3] += bfbits((v).y & 0xffff0000u); \
                      A[4] += bfbits((v).z << 16); A[5] += bfbits((v).z & 0xffff0000u); \
                      A[6] += bfbits((v).w << 16); A[7] += bfbits((v).w & 0xffff0000u); }

__global__ __launch_bounds__(256) void k_agg32(const unsigned short* __restrict__ xh,
                                               const unsigned* __restrict__ cur,
                                               const unsigned* __restrict__ slots,
                                               float* __restrict__ agg) {
    const int g  = blockIdx.x & 7;
    const int wv = (blockIdx.x >> 3) * 4 + (threadIdx.x >> 6);
    if (wv >= NPX / 2) return;
    const int n0 = g * NPX + 2 * wv;
    const int lane = threadIdx.x & 63;
    const int q = lane >> 4, l16 = lane & 15;

    const unsigned c0 = min(cur[n0], (unsigned)CAP);
    const unsigned c1 = min(cur[n0 + 1], (unsigned)CAP);

    const unsigned* sp = slots + (size_t)n0 * CAP;
    const unsigned lim = (lane < 32) ? c0 : c1;
    unsigned myslot = 0;
    if ((unsigned)(lane & 31) < lim) myslot = sp[lane];

    const uint4* xh4 = (const uint4*)xh;
    float A[8] = {0.f,0.f,0.f,0.f,0.f,0.f,0.f,0.f};
    float B[8] = {0.f,0.f,0.f,0.f,0.f,0.f,0.f,0.f};

    #pragma unroll
    for (int k = 0; k < 8; ++k) {
        const int idx = q + 4 * k;
        const unsigned sa = __shfl(myslot, idx);
        const unsigned sb = __shfl(myslot, 32 + idx);
        if (idx < (int)c0) {
            const uint4 v = xh4[(size_t)sa * 16 + l16];
            ADD8A(v, A);
        }
        if (idx < (int)c1) {
            const uint4 v = xh4[(size_t)sb * 16 + l16];
            ADD8A(v, B);
        }
    }

    #pragma unroll
    for (int j = 0; j < 8; ++j) {
        A[j] += __shfl_xor(A[j], 16); A[j] += __shfl_xor(A[j], 32);
        B[j] += __shfl_xor(B[j], 16); B[j] += __shfl_xor(B[j], 32);
    }

    if (q == 0) {
        float4* o = (float4*)(agg + (size_t)n0 * D + l16 * 8);
        o[0] = make_float4(A[0], A[1], A[2], A[3]);
        o[1] = make_float4(A[4], A[5], A[6], A[7]);
    } else if (q == 1) {
        float4* o = (float4*)(agg + (size_t)(n0 + 1) * D + l16 * 8);
        o[0] = make_float4(B[0], B[1], B[2], B[3]);
        o[1] = make_float4(B[4], B[5], B[6], B[7]);
    }
}

// =============== overflow fixup ===============
__global__ __launch_bounds__(256) void k_ovf_fix(const unsigned short* __restrict__ xh,
                                                 const unsigned* __restrict__ ovfn,
                                                 const unsigned* __restrict__ ovf,
                                                 float* __restrict__ agg) {
    const unsigned n = min(*ovfn, (unsigned)OVF_CAP);
    const int lane = threadIdx.x & 63;
    for (unsigned i = (unsigned)(threadIdx.x >> 6); i < n; i += 4) {
        const unsigned d = ovf[2 * i], s = ovf[2 * i + 1];
        const unsigned q = *(const unsigned*)(xh + (size_t)s * D + lane * 2);
        unsafeAtomicAdd(&agg[(size_t)d * D + lane * 2],     bfbits(q << 16));
        unsafeAtomicAdd(&agg[(size_t)d * D + lane * 2 + 1], bfbits(q & 0xffff0000u));
    }
}

// =============== MFMA finish GEMM (cur counts) ===============
__global__ __launch_bounds__(256) void gcn_gemm_mfma(
    float* __restrict__ io, const unsigned* __restrict__ rpc,
    const unsigned short* __restrict__ Bh, const float* __restrict__ b)
{
    __shared__ unsigned short As[128 * 128];
    __shared__ unsigned short Bs[128 * 128];
    __shared__ float scs[128], hass[128], bbs[128];

    const int t  = threadIdx.x;
    const int nb = blockIdx.x * 128;

    {
        const uint4* src = (const uint4*)Bh;
        uint4* dst = (uint4*)Bs;
        #pragma unroll
        for (int i = 0; i < 8; ++i) dst[t + i * 256] = src[t + i * 256];
    }
    for (int gid = t; gid < 2048; gid += 256) {
        const int m = gid >> 4, g = gid & 15;
        const int node = nb + m;
        float4 v0 = make_float4(0.f,0.f,0.f,0.f), v1 = v0;
        if (node < NN) {
            v0 = *(const float4*)(io + (size_t)node * D + g * 8);
            v1 = *(const float4*)(io + (size_t)node * D + g * 8 + 4);
        }
        uint4 o;
        o.x = f2bf(v0.x) | ((unsigned)f2bf(v0.y) << 16);
        o.y = f2bf(v0.z) | ((unsigned)f2bf(v0.w) << 16);
        o.z = f2bf(v1.x) | ((unsigned)f2bf(v1.y) << 16);
        o.w = f2bf(v1.z) | ((unsigned)f2bf(v1.w) << 16);
        *(uint4*)(As + (size_t)m * 128 + ((g ^ (m & 15)) * 8)) = o;
    }
    if (t < 128) {
        const int node = nb + t;
        const float c = (node < NN) ? (float)rpc[node] : 0.f;
        scs[t]  = 1.f / fmaxf(c, 1.f);
        hass[t] = (c > 0.f) ? 1.f : 0.f;
        bbs[t]  = b[t];
    }
    __syncthreads();

    const int w = t >> 6, lane = t & 63;
    const int wm = (w & 1) * 64, wn = (w >> 1) * 64;
    const int lr = lane & 15, lc = lane >> 4;

    f32x4 acc[4][4];
    #pragma unroll
    for (int mi = 0; mi < 4; ++mi)
        #pragma unroll
        for (int ni = 0; ni < 4; ++ni) acc[mi][ni] = (f32x4){0.f, 0.f, 0.f, 0.f};

    #pragma unroll
    for (int ks = 0; ks < 4; ++ks) {
        bf16x8 af[4], bg[4];
        #pragma unroll
        for (int mi = 0; mi < 4; ++mi) {
            const int m = wm + mi * 16 + lr;
            const int g = ks * 4 + lc;
            af[mi] = *(const bf16x8*)(As + (size_t)m * 128 + ((g ^ (m & 15)) * 8));
        }
        #pragma unroll
        for (int ni = 0; ni < 4; ++ni) {
            const int j  = wn + ni * 16 + lr;
            const int kc = ks * 4 + lc;
            bg[ni] = *(const bf16x8*)(Bs + ((size_t)(kc * 128 + j)) * 8);
        }
        #pragma unroll
        for (int mi = 0; mi < 4; ++mi)
            #pragma unroll
            for (int ni = 0; ni < 4; ++ni)
                acc[mi][ni] = __builtin_amdgcn_mfma_f32_16x16x32_bf16(
                    af[mi], bg[ni], acc[mi][ni], 0, 0, 0);
    }

    #pragma unroll
    for (int mi = 0; mi < 4; ++mi) {
        #pragma unroll
        for (int reg = 0; reg < 4; ++reg) {
            const int rl   = wm + mi * 16 + lc * 4 + reg;
            const int node = nb + rl;
            if (node >= NN) continue;
            const float s = scs[rl], hf = hass[rl];
            #pragma unroll
            for (int ni = 0; ni < 4; ++ni) {
                const int jl = wn + ni * 16 + lr;
                io[(size_t)node * D + jl] =
                    fmaxf(fmaf(acc[mi][ni][reg], s, bbs[jl] * hf), 0.f);
            }
        }
    }
}

// =============== deep fallback: atomic scatter + VALU gemm ===============
__global__ __launch_bounds__(256) void gcn_scatter(
    const float* __restrict__ x, const int* __restrict__ ei,
    float* __restrict__ agg, float* __restrict__ cnt)
{
    int tid    = blockIdx.x * 256 + threadIdx.x;
    int lane   = tid & 31;
    int eg     = tid >> 5;
    int stride = (gridDim.x * 256) >> 5;
    for (int e = eg; e < NE; e += stride) {
        int src = ei[e];
        int dst = ei[NE + e];
        const float4 xv = *reinterpret_cast<const float4*>(x + (size_t)src * D + lane * 4);
        float* ap = agg + (size_t)dst * D + lane * 4;
        unsafeAtomicAdd(ap + 0, xv.x);
        unsafeAtomicAdd(ap + 1, xv.y);
        unsafeAtomicAdd(ap + 2, xv.z);
        unsafeAtomicAdd(ap + 3, xv.w);
        if (lane == 0) unsafeAtomicAdd(cnt + dst, 1.0f);
    }
}

__global__ __launch_bounds__(256, 1) void gcn_gemm(
    float* __restrict__ io, const float* __restrict__ cnt,
    const float* __restrict__ W, const float* __restrict__ b)
{
    __shared__ float At[128 * 128];
    __shared__ float Wt[128 * 128];
    __shared__ float sc[128];
    __shared__ float hasf[128];

    const int t  = threadIdx.x;
    const int nb = blockIdx.x * 128;

    for (int i = t; i < 128 * 32; i += 256) {
        int j = i >> 5, c4 = i & 31;
        const float4 v = *reinterpret_cast<const float4*>(W + (size_t)j * D + c4 * 4);
        int k0 = c4 * 4;
        Wt[(k0 + 0) * 128 + (j ^ (((k0 + 0) & 12) << 1))] = v.x;
        Wt[(k0 + 1) * 128 + (j ^ (((k0 + 1) & 12) << 1))] = v.y;
        Wt[(k0 + 2) * 128 + (j ^ (((k0 + 2) & 12) << 1))] = v.z;
        Wt[(k0 + 3) * 128 + (j ^ (((k0 + 3) & 12) << 1))] = v.w;
    }
    for (int i = t; i < 128 * 32; i += 256) {
        int n = i >> 5, c4 = i & 31;
        int node = nb + n;
        float4 v = make_float4(0.f, 0.f, 0.f, 0.f);
        if (node < NN)
            v = *reinterpret_cast<const float4*>(io + (size_t)node * D + c4 * 4);
        int k0 = c4 * 4;
        At[(k0 + 0) * 128 + (n ^ (((k0 + 0) & 12) << 1))] = v.x;
        At[(k0 + 1) * 128 + (n ^ (((k0 + 1) & 12) << 1))] = v.y;
        At[(k0 + 2) * 128 + (n ^ (((k0 + 2) & 12) << 1))] = v.z;
        At[(k0 + 3) * 128 + (n ^ (((k0 + 3) & 12) << 1))] = v.w;
    }
    if (t < 128) {
        int node = nb + t;
        float c = (node < NN) ? cnt[node] : 0.f;
        sc[t]   = 1.0f / fmaxf(c, 1.0f);
        hasf[t] = (c > 0.f) ? 1.0f : 0.0f;
    }
    __syncthreads();

    const int tn = t >> 4;
    const int tj = t & 15;

    float bj[8];
    {
        const float4 b0 = *reinterpret_cast<const float4*>(b + tj * 8);
        const float4 b1 = *reinterpret_cast<const float4*>(b + tj * 8 + 4);
        bj[0]=b0.x; bj[1]=b0.y; bj[2]=b0.z; bj[3]=b0.w;
        bj[4]=b1.x; bj[5]=b1.y; bj[6]=b1.z; bj[7]=b1.w;
    }

    float acc[8][8];
    #pragma unroll
    for (int i = 0; i < 8; ++i)
        #pragma unroll
        for (int j = 0; j < 8; ++j) acc[i][j] = 0.f;

    #pragma unroll 2
    for (int k = 0; k < 128; ++k) {
        const int g = (k & 12) << 1;
        const float* Ar = At + k * 128;
        const float* Wr = Wt + k * 128;
        const float4 a0 = *reinterpret_cast<const float4*>(Ar + ((tn * 8) ^ g));
        const float4 a1 = *reinterpret_cast<const float4*>(Ar + ((tn * 8 + 4) ^ g));
        const float4 w0 = *reinterpret_cast<const float4*>(Wr + ((tj * 8) ^ g));
        const float4 w1 = *reinterpret_cast<const float4*>(Wr + ((tj * 8 + 4) ^ g));
        const float a[8] = {a0.x,a0.y,a0.z,a0.w,a1.x,a1.y,a1.z,a1.w};
        const float wv[8] = {w0.x,w0.y,w0.z,w0.w,w1.x,w1.y,w1.z,w1.w};
        #pragma unroll
        for (int i = 0; i < 8; ++i)
            #pragma unroll
            for (int j = 0; j < 8; ++j)
                acc[i][j] = fmaf(a[i], wv[j], acc[i][j]);
    }

    #pragma unroll
    for (int i = 0; i < 8; ++i) {
        const int node = nb + tn * 8 + i;
        if (node >= NN) continue;
        const float s  = sc[tn * 8 + i];
        const float hf = hasf[tn * 8 + i];
        float r[8];
        #pragma unroll
        for (int j = 0; j < 8; ++j)
            r[j] = fmaxf(fmaf(acc[i][j], s, bj[j] * hf), 0.f);
        float4* orow = reinterpret_cast<float4*>(io + (size_t)node * D + tj * 8);
        orow[0] = make_float4(r[0], r[1], r[2], r[3]);
        orow[1] = make_float4(r[4], r[5], r[6], r[7]);
    }
}

extern "C" void kernel_launch(void* const* d_in, const int* in_sizes, int n_in,
                              void* d_out, int out_size, void* d_ws, size_t ws_size,
                              hipStream_t stream)
{
    const float* x  = (const float*)d_in[0];
    const int*   ei = (const int*)d_in[1];
    // d_in[2] = edge_features: unused by the reference computation
    const float* W  = (const float*)d_in[3];
    const float* b  = (const float*)d_in[4];
    float* out = (float*)d_out;            // agg f32 buffer, then final output in-place

    const int ngemm = (NN + 127) / 128;
    const int naggb = ((NPX / 2 + 3) / 4) * 8;
    char* ws = (char*)d_ws;

    if (ws_size >= (size_t)W3_NEED) {
        // W3: route -> slot-fill (single ei pass, low-pollution scatter)
        unsigned short* xh = (unsigned short*)(ws + W3_XH);
        unsigned* slots    = (unsigned*)(ws + W3_SLOTS);
        unsigned* cur      = (unsigned*)(ws + W3_CUR);
        unsigned* ovfn     = (unsigned*)(ws + W3_OVFN);
        unsigned* ovf      = (unsigned*)(ws + W3_OVF);
        unsigned short* Bh = (unsigned short*)(ws + W3_BH);
        unsigned* fcnt     = (unsigned*)(ws + W3_FCNT);
        unsigned* fifo     = (unsigned*)(ws + W3_FIFO);

        hipMemsetAsync(cur, 0, 400128, stream);        // covers cur + ovfn
        k_route_prep<<<RBLK + SP_CASTX + 8, 256, 0, stream>>>(
            x, W, ei, cur, slots, ovfn, ovf, fcnt, fifo, (unsigned*)xh, Bh);
        k_slot_fill<<<RBLK * 8, 256, 0, stream>>>(fcnt, fifo, cur, slots, ovfn, ovf);
        k_agg32<<<naggb, 256, 0, stream>>>(xh, cur, slots, out);
        k_ovf_fix<<<1, 256, 0, stream>>>(xh, ovfn, ovf, out);
        gcn_gemm_mfma<<<ngemm, 256, 0, stream>>>(out, cur, Bh, b);
    } else if (ws_size >= (size_t)W2_NEED) {
        // W2: r14-proven pipeline
        unsigned short* xh = (unsigned short*)(ws + W2_XH);
        unsigned* slots    = (unsigned*)(ws + W2_SLOTS);
        unsigned* cur      = (unsigned*)(ws + W2_CUR);
        unsigned* ovfn     = (unsigned*)(ws + W2_OVFN);
        unsigned* ovf      = (unsigned*)(ws + W2_OVF);
        unsigned short* Bh = (unsigned short*)(ws + W2_BH);

        hipMemsetAsync(cur, 0, 400128, stream);
        k_scatter_prep<<<SP_GRID, 256, 0, stream>>>(x, W, ei, cur, slots, ovfn, ovf,
                                                    (unsigned*)xh, Bh);
        k_agg32<<<naggb, 256, 0, stream>>>(xh, cur, slots, out);
        k_ovf_fix<<<1, 256, 0, stream>>>(xh, ovfn, ovf, out);
        gcn_gemm_mfma<<<ngemm, 256, 0, stream>>>(out, cur, Bh, b);
    } else {
        float* cnt = (float*)d_ws;
        hipMemsetAsync(d_out, 0, (size_t)NN * D * sizeof(float), stream);
        hipMemsetAsync(d_ws,  0, (size_t)NN * sizeof(float), stream);
        gcn_scatter<<<4096, 256, 0, stream>>>(x, ei, out, cnt);
        gcn_gemm<<<ngemm, 256, 0, stream>>>(out, cnt, W, b);
    }
}

// Round 16
// 174.934 us; speedup vs baseline: 1.0557x; 1.0557x over previous
//
#include <hip/hip_runtime.h>

#define NN 100000
#define NE 1600000
#define D  128
#define CAP 32
#define OVF_CAP 65536
#define SCAN_CHUNK 1024
#define NCHUNK ((NN + SCAN_CHUNK - 1) / SCAN_CHUNK)   // 98
#define NXCD 8
#define NPX  (NN / NXCD)                              // 12500 nodes per XCD slice

// ---- FULL-path workspace layout (bytes), ~39.4 MB ----
#define W2_XH    0u             // NN*D bf16 = 25,600,000
#define W2_SLOTS 25600000u      // NN*CAP u32 = 12,800,000
#define W2_CUR   38400000u      // NN u32 (+pad; memset 400,128 covers OVFN)
#define W2_OVFN  38800000u      // 1 u32
#define W2_OVF   38800128u      // OVF_CAP * 8B
#define W2_BH    39324416u      // 32,768
#define W2_NEED  39357184u

// ---- MID-path workspace layout (CSR pipeline), ~32.8 MB ----
#define WM_COUNTS   0u
#define WM_ROWPTR   400128u
#define WM_PARTIALS 800768u
#define WM_SORTED   801280u
#define WM_BH       7201280u
#define WM_XH       7234048u
#define WM_NEED     (7234048u + (unsigned)NN * (unsigned)D * 2u)  // 32,834,048

// fused scatter+prep block ranges
#define SP_SCAT  2048
#define SP_CASTX 6250
#define SP_GRID  (SP_SCAT + SP_CASTX + 8)

typedef __attribute__((ext_vector_type(8))) short bf16x8;
typedef __attribute__((ext_vector_type(4))) float f32x4;

__device__ __forceinline__ unsigned short f2bf(float f) {   // RNE f32 -> bf16
    union { float f; unsigned u; } v; v.f = f;
    unsigned r = v.u + 0x7fffu + ((v.u >> 16) & 1u);
    return (unsigned short)(r >> 16);
}
__device__ __forceinline__ float bfbits(unsigned hi) {      // bf16 bits in high half -> f32
    union { unsigned u; float f; } v; v.u = hi; return v.f;
}

__device__ __forceinline__ void cast_x_body(const float* x, unsigned* xh4, int i) {
    const float4 v0 = *((const float4*)x + i * 2);
    const float4 v1 = *((const float4*)x + i * 2 + 1);
    uint4 o;
    o.x = f2bf(v0.x) | ((unsigned)f2bf(v0.y) << 16);
    o.y = f2bf(v0.z) | ((unsigned)f2bf(v0.w) << 16);
    o.z = f2bf(v1.x) | ((unsigned)f2bf(v1.y) << 16);
    o.w = f2bf(v1.z) | ((unsigned)f2bf(v1.w) << 16);
    *((uint4*)xh4 + i) = o;
}
__device__ __forceinline__ void cast_w_body(const float* W, unsigned short* Bh, int idx) {
    const int j = idx >> 4, kc = idx & 15;
    const float4 w0 = *(const float4*)(W + (size_t)j * D + kc * 8);
    const float4 w1 = *(const float4*)(W + (size_t)j * D + kc * 8 + 4);
    unsigned short* o = Bh + ((size_t)(kc * 128 + j)) * 8;
    o[0] = f2bf(w0.x); o[1] = f2bf(w0.y); o[2] = f2bf(w0.z); o[3] = f2bf(w0.w);
    o[4] = f2bf(w1.x); o[5] = f2bf(w1.y); o[6] = f2bf(w1.z); o[7] = f2bf(w1.w);
}

// =============== FULL K1: fused slot scatter (XCD-local) + casts ===============
__global__ __launch_bounds__(256) void k_scatter_prep(const float* __restrict__ x,
                                                      const float* __restrict__ W,
                                                      const int* __restrict__ ei,
                                                      unsigned* __restrict__ cur,
                                                      unsigned* __restrict__ slots,
                                                      unsigned* __restrict__ ovfn,
                                                      unsigned* __restrict__ ovf,
                                                      unsigned* __restrict__ xh4,
                                                      unsigned short* __restrict__ Bh) {
    const int bid = blockIdx.x, t = threadIdx.x;
    if (bid < SP_SCAT) {
        const unsigned lo = (bid & 7) * NPX;
        const int nth = (SP_SCAT >> 3) * 256;      // 65536 threads per XCD group
        const int tid = (bid >> 3) * 256 + t;

        auto put = [&](unsigned d, unsigned s) {
            if (d - lo < NPX) {
                const unsigned p = atomicAdd(&cur[d], 1u);
                if (p < CAP) slots[(size_t)d * CAP + p] = s;
                else {
                    const unsigned o = atomicAdd(ovfn, 1u);
                    if (o < OVF_CAP) { ovf[2 * o] = d; ovf[2 * o + 1] = s; }
                }
            }
        };

        int e = tid;
        for (; e + 3 * nth < NE; e += 4 * nth) {
            const unsigned d0 = (unsigned)ei[NE + e];
            const unsigned d1 = (unsigned)ei[NE + e + nth];
            const unsigned d2 = (unsigned)ei[NE + e + 2 * nth];
            const unsigned d3 = (unsigned)ei[NE + e + 3 * nth];
            const unsigned s0 = (unsigned)ei[e];
            const unsigned s1 = (unsigned)ei[e + nth];
            const unsigned s2 = (unsigned)ei[e + 2 * nth];
            const unsigned s3 = (unsigned)ei[e + 3 * nth];
            put(d0, s0); put(d1, s1); put(d2, s2); put(d3, s3);
        }
        for (; e < NE; e += nth) put((unsigned)ei[NE + e], (unsigned)ei[e]);
    } else if (bid < SP_SCAT + SP_CASTX) {
        cast_x_body(x, xh4, (bid - SP_SCAT) * 256 + t);
    } else {
        const int idx = (bid - SP_SCAT - SP_CASTX) * 256 + t;
        if (idx < 128 * 16) cast_w_body(W, Bh, idx);
    }
}

// =============== FULL K2: aggregate — 2 nodes/wave, quarter-wave uint4, 32 rows in flight ===============
#define ADD8A(v, A) { A[0] += bfbits((v).x << 16); A[1] += bfbits((v).x & 0xffff0000u); \
                      A[2] += bfbits((v).y << 16); A[3] += bfbits((v).y & 0xffff0000u); \
                      A[4] += bfbits((v).z << 16); A[5] += bfbits((v).z & 0xffff0000u); \
                      A[6] += bfbits((v).w << 16); A[7] += bfbits((v).w & 0xffff0000u); }

__global__ __launch_bounds__(256) void k_agg32(const unsigned short* __restrict__ xh,
                                               const unsigned* __restrict__ cur,
                                               const unsigned* __restrict__ slots,
                                               float* __restrict__ agg) {
    const int g  = blockIdx.x & 7;
    const int wv = (blockIdx.x >> 3) * 4 + (threadIdx.x >> 6);   // pair index in slice
    if (wv >= NPX / 2) return;
    const int n0 = g * NPX + 2 * wv;                             // nodes n0, n0+1
    const int lane = threadIdx.x & 63;
    const int q = lane >> 4, l16 = lane & 15;

    const unsigned c0 = min(cur[n0], (unsigned)CAP);
    const unsigned c1 = min(cur[n0 + 1], (unsigned)CAP);

    // slots of n0 (lanes 0-31) and n0+1 (lanes 32-63): one contiguous 256B load
    const unsigned* sp = slots + (size_t)n0 * CAP;
    const unsigned lim = (lane < 32) ? c0 : c1;
    unsigned myslot = 0;
    if ((unsigned)(lane & 31) < lim) myslot = sp[lane];

    const uint4* xh4 = (const uint4*)xh;
    float A[8] = {0.f,0.f,0.f,0.f,0.f,0.f,0.f,0.f};
    float B[8] = {0.f,0.f,0.f,0.f,0.f,0.f,0.f,0.f};

    #pragma unroll
    for (int k = 0; k < 8; ++k) {
        const int idx = q + 4 * k;                // 0..31, uniform per quarter
        const unsigned sa = __shfl(myslot, idx);
        const unsigned sb = __shfl(myslot, 32 + idx);
        if (idx < (int)c0) {
            const uint4 v = xh4[(size_t)sa * 16 + l16];
            ADD8A(v, A);
        }
        if (idx < (int)c1) {
            const uint4 v = xh4[(size_t)sb * 16 + l16];
            ADD8A(v, B);
        }
    }

    #pragma unroll
    for (int j = 0; j < 8; ++j) {
        A[j] += __shfl_xor(A[j], 16); A[j] += __shfl_xor(A[j], 32);
        B[j] += __shfl_xor(B[j], 16); B[j] += __shfl_xor(B[j], 32);
    }

    if (q == 0) {
        float4* o = (float4*)(agg + (size_t)n0 * D + l16 * 8);
        o[0] = make_float4(A[0], A[1], A[2], A[3]);
        o[1] = make_float4(A[4], A[5], A[6], A[7]);
    } else if (q == 1) {
        float4* o = (float4*)(agg + (size_t)(n0 + 1) * D + l16 * 8);
        o[0] = make_float4(B[0], B[1], B[2], B[3]);
        o[1] = make_float4(B[4], B[5], B[6], B[7]);
    }
}

// =============== FULL K3: overflow fixup ===============
__global__ __launch_bounds__(256) void k_ovf_fix(const unsigned short* __restrict__ xh,
                                                 const unsigned* __restrict__ ovfn,
                                                 const unsigned* __restrict__ ovf,
                                                 float* __restrict__ agg) {
    const unsigned n = min(*ovfn, (unsigned)OVF_CAP);
    const int lane = threadIdx.x & 63;
    for (unsigned i = (unsigned)(threadIdx.x >> 6); i < n; i += 4) {
        const unsigned d = ovf[2 * i], s = ovf[2 * i + 1];
        const unsigned q = *(const unsigned*)(xh + (size_t)s * D + lane * 2);
        unsafeAtomicAdd(&agg[(size_t)d * D + lane * 2],     bfbits(q << 16));
        unsafeAtomicAdd(&agg[(size_t)d * D + lane * 2 + 1], bfbits(q & 0xffff0000u));
    }
}

// =============== MID path (CSR pipeline) ===============
__global__ __launch_bounds__(256) void k_prep_hist2(const float* __restrict__ x,
                                                    const float* __restrict__ W,
                                                    const int* __restrict__ ei,
                                                    unsigned* __restrict__ counts,
                                                    unsigned* __restrict__ xh4,
                                                    unsigned short* __restrict__ Bh) {
    const int bid = blockIdx.x, t = threadIdx.x;
    if (bid < 6250) {
        const int e = bid * 256 + t;
        if (e < NE) atomicAdd(&counts[(unsigned)ei[NE + e]], 1u);
    } else if (bid < 12500) {
        cast_x_body(x, xh4, (bid - 6250) * 256 + t);
    } else {
        const int idx = (bid - 12500) * 256 + t;
        if (idx < 128 * 16) cast_w_body(W, Bh, idx);
    }
}

__global__ __launch_bounds__(SCAN_CHUNK) void k_scan(const unsigned* __restrict__ counts,
                                                     unsigned* __restrict__ row_ptr,
                                                     unsigned* __restrict__ partials) {
    __shared__ unsigned s[SCAN_CHUNK];
    const int t = threadIdx.x;
    const int g = blockIdx.x * SCAN_CHUNK + t;
    unsigned v = (g < NN) ? counts[g] : 0u;
    s[t] = v;
    __syncthreads();
    for (int off = 1; off < SCAN_CHUNK; off <<= 1) {
        unsigned add = (t >= off) ? s[t - off] : 0u;
        __syncthreads();
        s[t] += add;
        __syncthreads();
    }
    if (g < NN) row_ptr[g] = s[t] - v;
    if (t == SCAN_CHUNK - 1) partials[blockIdx.x] = s[t];
}

__global__ __launch_bounds__(128) void k_scan_partials(unsigned* __restrict__ partials) {
    __shared__ unsigned s[128];
    const int t = threadIdx.x;
    unsigned v = (t < NCHUNK) ? partials[t] : 0u;
    s[t] = v;
    __syncthreads();
    for (int off = 1; off < 128; off <<= 1) {
        unsigned add = (t >= off) ? s[t - off] : 0u;
        __syncthreads();
        s[t] += add;
        __syncthreads();
    }
    if (t < NCHUNK) partials[t] = s[t] - v;
}

__global__ __launch_bounds__(SCAN_CHUNK) void k_add_offsets(unsigned* __restrict__ row_ptr,
                                                            const unsigned* __restrict__ partials,
                                                            unsigned* __restrict__ cur) {
    const int g = blockIdx.x * SCAN_CHUNK + threadIdx.x;
    if (g < NN) {
        const unsigned v = row_ptr[g] + partials[blockIdx.x];
        row_ptr[g] = v;
        cur[g] = v;
    }
    if (g == 0) row_ptr[NN] = NE;
}

__global__ __launch_bounds__(256) void k_place2(const int* __restrict__ ei,
                                                unsigned* __restrict__ cur,
                                                unsigned* __restrict__ sorted_src) {
    const unsigned lo = (blockIdx.x & 7) * NPX;
    const int nth = (gridDim.x >> 3) * 256;
    const int tid = (blockIdx.x >> 3) * 256 + threadIdx.x;
    int e = tid;
    for (; e + 3 * nth < NE; e += 4 * nth) {
        const unsigned d0 = (unsigned)ei[NE + e];
        const unsigned d1 = (unsigned)ei[NE + e + nth];
        const unsigned d2 = (unsigned)ei[NE + e + 2 * nth];
        const unsigned d3 = (unsigned)ei[NE + e + 3 * nth];
        const unsigned s0 = (unsigned)ei[e];
        const unsigned s1 = (unsigned)ei[e + nth];
        const unsigned s2 = (unsigned)ei[e + 2 * nth];
        const unsigned s3 = (unsigned)ei[e + 3 * nth];
        if (d0 - lo < NPX) sorted_src[atomicAdd(&cur[d0], 1u)] = s0;
        if (d1 - lo < NPX) sorted_src[atomicAdd(&cur[d1], 1u)] = s1;
        if (d2 - lo < NPX) sorted_src[atomicAdd(&cur[d2], 1u)] = s2;
        if (d3 - lo < NPX) sorted_src[atomicAdd(&cur[d3], 1u)] = s3;
    }
    for (; e < NE; e += nth) {
        const unsigned d = (unsigned)ei[NE + e];
        if (d - lo < NPX) sorted_src[atomicAdd(&cur[d], 1u)] = (unsigned)ei[e];
    }
}

__global__ __launch_bounds__(256) void k_aggregate_hx(const unsigned short* __restrict__ xh,
                                                      const unsigned* __restrict__ rp,
                                                      const unsigned* __restrict__ srt,
                                                      float* __restrict__ agg) {
    const int wave = (blockIdx.x & 7) * NPX + (blockIdx.x >> 3) * 4 + (threadIdx.x >> 6);
    const int lane = threadIdx.x & 63;
    if (wave >= NN) return;
    const int half = lane >> 5;
    const int c8   = lane & 31;
    const unsigned b0 = rp[wave], b1 = rp[wave + 1];

    float a0=0.f,a1=0.f,a2=0.f,a3=0.f, c0=0.f,c1=0.f,c2=0.f,c3=0.f;
    unsigned i = b0 + half;
    for (; i + 6 < b1; i += 8) {
        uint2 q0 = *(const uint2*)(xh + (size_t)srt[i]     * D + c8 * 4);
        uint2 q1 = *(const uint2*)(xh + (size_t)srt[i + 2] * D + c8 * 4);
        uint2 q2 = *(const uint2*)(xh + (size_t)srt[i + 4] * D + c8 * 4);
        uint2 q3 = *(const uint2*)(xh + (size_t)srt[i + 6] * D + c8 * 4);
        a0 += bfbits(q0.x << 16); a1 += bfbits(q0.x & 0xffff0000u);
        a2 += bfbits(q0.y << 16); a3 += bfbits(q0.y & 0xffff0000u);
        c0 += bfbits(q1.x << 16); c1 += bfbits(q1.x & 0xffff0000u);
        c2 += bfbits(q1.y << 16); c3 += bfbits(q1.y & 0xffff0000u);
        a0 += bfbits(q2.x << 16); a1 += bfbits(q2.x & 0xffff0000u);
        a2 += bfbits(q2.y << 16); a3 += bfbits(q2.y & 0xffff0000u);
        c0 += bfbits(q3.x << 16); c1 += bfbits(q3.x & 0xffff0000u);
        c2 += bfbits(q3.y << 16); c3 += bfbits(q3.y & 0xffff0000u);
    }
    for (; i < b1; i += 2) {
        const uint2 p = *(const uint2*)(xh + (size_t)srt[i] * D + c8 * 4);
        a0 += bfbits(p.x << 16); a1 += bfbits(p.x & 0xffff0000u);
        a2 += bfbits(p.y << 16); a3 += bfbits(p.y & 0xffff0000u);
    }
    float s0 = a0 + c0, s1 = a1 + c1, s2 = a2 + c2, s3 = a3 + c3;
    s0 += __shfl_xor(s0, 32); s1 += __shfl_xor(s1, 32);
    s2 += __shfl_xor(s2, 32); s3 += __shfl_xor(s3, 32);
    if (half == 0)
        *(float4*)(agg + (size_t)wave * D + c8 * 4) = make_float4(s0, s1, s2, s3);
}

// =============== MFMA finish GEMM (MODE 0: rp-diff counts; 1: cur counts) ===============
template <int MODE>
__global__ __launch_bounds__(256) void gcn_gemm_mfma(
    float* __restrict__ io, const unsigned* __restrict__ rpc,
    const unsigned short* __restrict__ Bh, const float* __restrict__ b)
{
    __shared__ unsigned short As[128 * 128];
    __shared__ unsigned short Bs[128 * 128];
    __shared__ float scs[128], hass[128], bbs[128];

    const int t  = threadIdx.x;
    const int nb = blockIdx.x * 128;

    {
        const uint4* src = (const uint4*)Bh;
        uint4* dst = (uint4*)Bs;
        #pragma unroll
        for (int i = 0; i < 8; ++i) dst[t + i * 256] = src[t + i * 256];
    }
    for (int gid = t; gid < 2048; gid += 256) {
        const int m = gid >> 4, g = gid & 15;
        const int node = nb + m;
        float4 v0 = make_float4(0.f,0.f,0.f,0.f), v1 = v0;
        if (node < NN) {
            v0 = *(const float4*)(io + (size_t)node * D + g * 8);
            v1 = *(const float4*)(io + (size_t)node * D + g * 8 + 4);
        }
        uint4 o;
        o.x = f2bf(v0.x) | ((unsigned)f2bf(v0.y) << 16);
        o.y = f2bf(v0.z) | ((unsigned)f2bf(v0.w) << 16);
        o.z = f2bf(v1.x) | ((unsigned)f2bf(v1.y) << 16);
        o.w = f2bf(v1.z) | ((unsigned)f2bf(v1.w) << 16);
        *(uint4*)(As + (size_t)m * 128 + ((g ^ (m & 15)) * 8)) = o;
    }
    if (t < 128) {
        const int node = nb + t;
        float c = 0.f;
        if (node < NN)
            c = (MODE == 0) ? (float)(rpc[node + 1] - rpc[node]) : (float)rpc[node];
        scs[t]  = 1.f / fmaxf(c, 1.f);
        hass[t] = (c > 0.f) ? 1.f : 0.f;
        bbs[t]  = b[t];
    }
    __syncthreads();

    const int w = t >> 6, lane = t & 63;
    const int wm = (w & 1) * 64, wn = (w >> 1) * 64;
    const int lr = lane & 15, lc = lane >> 4;

    f32x4 acc[4][4];
    #pragma unroll
    for (int mi = 0; mi < 4; ++mi)
        #pragma unroll
        for (int ni = 0; ni < 4; ++ni) acc[mi][ni] = (f32x4){0.f, 0.f, 0.f, 0.f};

    #pragma unroll
    for (int ks = 0; ks < 4; ++ks) {
        bf16x8 af[4], bg[4];
        #pragma unroll
        for (int mi = 0; mi < 4; ++mi) {
            const int m = wm + mi * 16 + lr;
            const int g = ks * 4 + lc;
            af[mi] = *(const bf16x8*)(As + (size_t)m * 128 + ((g ^ (m & 15)) * 8));
        }
        #pragma unroll
        for (int ni = 0; ni < 4; ++ni) {
            const int j  = wn + ni * 16 + lr;
            const int kc = ks * 4 + lc;
            bg[ni] = *(const bf16x8*)(Bs + ((size_t)(kc * 128 + j)) * 8);
        }
        #pragma unroll
        for (int mi = 0; mi < 4; ++mi)
            #pragma unroll
            for (int ni = 0; ni < 4; ++ni)
                acc[mi][ni] = __builtin_amdgcn_mfma_f32_16x16x32_bf16(
                    af[mi], bg[ni], acc[mi][ni], 0, 0, 0);
    }

    #pragma unroll
    for (int mi = 0; mi < 4; ++mi) {
        #pragma unroll
        for (int reg = 0; reg < 4; ++reg) {
            const int rl   = wm + mi * 16 + lc * 4 + reg;
            const int node = nb + rl;
            if (node >= NN) continue;
            const float s = scs[rl], hf = hass[rl];
            #pragma unroll
            for (int ni = 0; ni < 4; ++ni) {
                const int jl = wn + ni * 16 + lr;
                io[(size_t)node * D + jl] =
                    fmaxf(fmaf(acc[mi][ni][reg], s, bbs[jl] * hf), 0.f);
            }
        }
    }
}

// =============== deep fallback: atomic scatter + VALU gemm ===============
__global__ __launch_bounds__(256) void gcn_scatter(
    const float* __restrict__ x, const int* __restrict__ ei,
    float* __restrict__ agg, float* __restrict__ cnt)
{
    int tid    = blockIdx.x * 256 + threadIdx.x;
    int lane   = tid & 31;
    int eg     = tid >> 5;
    int stride = (gridDim.x * 256) >> 5;
    for (int e = eg; e < NE; e += stride) {
        int src = ei[e];
        int dst = ei[NE + e];
        const float4 xv = *reinterpret_cast<const float4*>(x + (size_t)src * D + lane * 4);
        float* ap = agg + (size_t)dst * D + lane * 4;
        unsafeAtomicAdd(ap + 0, xv.x);
        unsafeAtomicAdd(ap + 1, xv.y);
        unsafeAtomicAdd(ap + 2, xv.z);
        unsafeAtomicAdd(ap + 3, xv.w);
        if (lane == 0) unsafeAtomicAdd(cnt + dst, 1.0f);
    }
}

__global__ __launch_bounds__(256, 1) void gcn_gemm(
    float* __restrict__ io, const float* __restrict__ cnt,
    const float* __restrict__ W, const float* __restrict__ b)
{
    __shared__ float At[128 * 128];
    __shared__ float Wt[128 * 128];
    __shared__ float sc[128];
    __shared__ float hasf[128];

    const int t  = threadIdx.x;
    const int nb = blockIdx.x * 128;

    for (int i = t; i < 128 * 32; i += 256) {
        int j = i >> 5, c4 = i & 31;
        const float4 v = *reinterpret_cast<const float4*>(W + (size_t)j * D + c4 * 4);
        int k0 = c4 * 4;
        Wt[(k0 + 0) * 128 + (j ^ (((k0 + 0) & 12) << 1))] = v.x;
        Wt[(k0 + 1) * 128 + (j ^ (((k0 + 1) & 12) << 1))] = v.y;
        Wt[(k0 + 2) * 128 + (j ^ (((k0 + 2) & 12) << 1))] = v.z;
        Wt[(k0 + 3) * 128 + (j ^ (((k0 + 3) & 12) << 1))] = v.w;
    }
    for (int i = t; i < 128 * 32; i += 256) {
        int n = i >> 5, c4 = i & 31;
        int node = nb + n;
        float4 v = make_float4(0.f, 0.f, 0.f, 0.f);
        if (node < NN)
            v = *reinterpret_cast<const float4*>(io + (size_t)node * D + c4 * 4);
        int k0 = c4 * 4;
        At[(k0 + 0) * 128 + (n ^ (((k0 + 0) & 12) << 1))] = v.x;
        At[(k0 + 1) * 128 + (n ^ (((k0 + 1) & 12) << 1))] = v.y;
        At[(k0 + 2) * 128 + (n ^ (((k0 + 2) & 12) << 1))] = v.z;
        At[(k0 + 3) * 128 + (n ^ (((k0 + 3) & 12) << 1))] = v.w;
    }
    if (t < 128) {
        int node = nb + t;
        float c = (node < NN) ? cnt[node] : 0.f;
        sc[t]   = 1.0f / fmaxf(c, 1.0f);
        hasf[t] = (c > 0.f) ? 1.0f : 0.0f;
    }
    __syncthreads();

    const int tn = t >> 4;
    const int tj = t & 15;

    float bj[8];
    {
        const float4 b0 = *reinterpret_cast<const float4*>(b + tj * 8);
        const float4 b1 = *reinterpret_cast<const float4*>(b + tj * 8 + 4);
        bj[0]=b0.x; bj[1]=b0.y; bj[2]=b0.z; bj[3]=b0.w;
        bj[4]=b1.x; bj[5]=b1.y; bj[6]=b1.z; bj[7]=b1.w;
    }

    float acc[8][8];
    #pragma unroll
    for (int i = 0; i < 8; ++i)
        #pragma unroll
        for (int j = 0; j < 8; ++j) acc[i][j] = 0.f;

    #pragma unroll 2
    for (int k = 0; k < 128; ++k) {
        const int g = (k & 12) << 1;
        const float* Ar = At + k * 128;
        const float* Wr = Wt + k * 128;
        const float4 a0 = *reinterpret_cast<const float4*>(Ar + ((tn * 8) ^ g));
        const float4 a1 = *reinterpret_cast<const float4*>(Ar + ((tn * 8 + 4) ^ g));
        const float4 w0 = *reinterpret_cast<const float4*>(Wr + ((tj * 8) ^ g));
        const float4 w1 = *reinterpret_cast<const float4*>(Wr + ((tj * 8 + 4) ^ g));
        const float a[8] = {a0.x,a0.y,a0.z,a0.w,a1.x,a1.y,a1.z,a1.w};
        const float wv[8] = {w0.x,w0.y,w0.z,w0.w,w1.x,w1.y,w1.z,w1.w};
        #pragma unroll
        for (int i = 0; i < 8; ++i)
            #pragma unroll
            for (int j = 0; j < 8; ++j)
                acc[i][j] = fmaf(a[i], wv[j], acc[i][j]);
    }

    #pragma unroll
    for (int i = 0; i < 8; ++i) {
        const int node = nb + tn * 8 + i;
        if (node >= NN) continue;
        const float s  = sc[tn * 8 + i];
        const float hf = hasf[tn * 8 + i];
        float r[8];
        #pragma unroll
        for (int j = 0; j < 8; ++j)
            r[j] = fmaxf(fmaf(acc[i][j], s, bj[j] * hf), 0.f);
        float4* orow = reinterpret_cast<float4*>(io + (size_t)node * D + tj * 8);
        orow[0] = make_float4(r[0], r[1], r[2], r[3]);
        orow[1] = make_float4(r[4], r[5], r[6], r[7]);
    }
}

extern "C" void kernel_launch(void* const* d_in, const int* in_sizes, int n_in,
                              void* d_out, int out_size, void* d_ws, size_t ws_size,
                              hipStream_t stream)
{
    const float* x  = (const float*)d_in[0];
    const int*   ei = (const int*)d_in[1];
    // d_in[2] = edge_features: unused by the reference computation
    const float* W  = (const float*)d_in[3];
    const float* b  = (const float*)d_in[4];
    float* out = (float*)d_out;            // agg f32 buffer, then final output in-place

    const int ngemm = (NN + 127) / 128;
    char* ws = (char*)d_ws;

    if (ws_size >= (size_t)W2_NEED) {
        // FULL: fused scatter+prep; 2-node-per-wave agg; ovf; gemm  (r14-proven best)
        unsigned short* xh = (unsigned short*)(ws + W2_XH);
        unsigned* slots    = (unsigned*)(ws + W2_SLOTS);
        unsigned* cur      = (unsigned*)(ws + W2_CUR);
        unsigned* ovfn     = (unsigned*)(ws + W2_OVFN);
        unsigned* ovf      = (unsigned*)(ws + W2_OVF);
        unsigned short* Bh = (unsigned short*)(ws + W2_BH);

        hipMemsetAsync(cur, 0, 400128, stream);        // covers cur + ovfn
        k_scatter_prep<<<SP_GRID, 256, 0, stream>>>(x, W, ei, cur, slots, ovfn, ovf,
                                                    (unsigned*)xh, Bh);
        const int naggb = ((NPX / 2 + 3) / 4) * 8;     // 1563 * 8 blocks
        k_agg32<<<naggb, 256, 0, stream>>>(xh, cur, slots, out);
        k_ovf_fix<<<1, 256, 0, stream>>>(xh, ovfn, ovf, out);
        gcn_gemm_mfma<1><<<ngemm, 256, 0, stream>>>(out, cur, Bh, b);
    } else if (ws_size >= (size_t)WM_NEED) {
        // MID: CSR pipeline
        unsigned* counts   = (unsigned*)(ws + WM_COUNTS);
        unsigned* row_ptr  = (unsigned*)(ws + WM_ROWPTR);
        unsigned* partials = (unsigned*)(ws + WM_PARTIALS);
        unsigned* sorted   = (unsigned*)(ws + WM_SORTED);
        unsigned short* Bh = (unsigned short*)(ws + WM_BH);
        unsigned short* xh = (unsigned short*)(ws + WM_XH);

        hipMemsetAsync(counts, 0, (size_t)NN * sizeof(unsigned), stream);
        k_prep_hist2<<<12508, 256, 0, stream>>>(x, W, ei, counts, (unsigned*)xh, Bh);
        k_scan<<<NCHUNK, SCAN_CHUNK, 0, stream>>>(counts, row_ptr, partials);
        k_scan_partials<<<1, 128, 0, stream>>>(partials);
        k_add_offsets<<<NCHUNK, SCAN_CHUNK, 0, stream>>>(row_ptr, partials, counts);
        k_place2<<<2048, 256, 0, stream>>>(ei, counts, sorted);
        k_aggregate_hx<<<(NPX / 4) * 8, 256, 0, stream>>>(xh, row_ptr, sorted, out);
        gcn_gemm_mfma<0><<<ngemm, 256, 0, stream>>>(out, row_ptr, Bh, b);
    } else {
        float* cnt = (float*)d_ws;
        hipMemsetAsync(d_out, 0, (size_t)NN * D * sizeof(float), stream);
        hipMemsetAsync(d_ws,  0, (size_t)NN * sizeof(float), stream);
        gcn_scatter<<<4096, 256, 0, stream>>>(x, ei, out, cnt);
        gcn_gemm<<<ngemm, 256, 0, stream>>>(out, cnt, W, b);
    }
}